// Round 6
// baseline (109.989 us; speedup 1.0000x reference)
//
#include <hip/hip_runtime.h>
#include <cstdint>
#include <cstddef>

// NetGrad J = W5 D4 W4 D3 W3 D2 W2 D1 W1, output [B,3,64].
// Single fused kernel per 16-sample block: fwd chain (H ping-pong in LDS,
// G1..G4 in registers, same lane mapping as bwd consumer) then bwd chain
// (48-row C in LDS, row layout o*16+s). MFMA f16 hi/lo split (hh+hl+lh).
// k-loops software-pipelined: global B-frags double-buffered in registers.

typedef _Float16 half_t;
typedef __attribute__((ext_vector_type(8))) _Float16 half8;
typedef __attribute__((ext_vector_type(4))) float f32x4;

#define MFMA16(a, b, c) __builtin_amdgcn_mfma_f32_16x16x32_f16(a, b, c, 0, 0, 0)

constexpr int Bsz = 8192;
constexpr int D   = 256;
constexpr int LDA = 264;          // LDS row stride in halves (528 B)

// ---------------- prep: split (native) + transpose-split all weights ----------------
__global__ __launch_bounds__(256)
void prep_split(const float* __restrict__ W1, const float* __restrict__ W2,
                const float* __restrict__ W3, const float* __restrict__ W4,
                half_t* W1h, half_t* W1l, half_t* T1h, half_t* T1l,
                half_t* W2h, half_t* W2l, half_t* T2h, half_t* T2l,
                half_t* W3h, half_t* W3l, half_t* T3h, half_t* T3l,
                half_t* W4h, half_t* W4l, half_t* T4h, half_t* T4l)
{
    __shared__ float tile[32][33];
    const int bid = blockIdx.x;
    const float* src; half_t *sh, *sl, *th, *tl; int C, bx, by;
    if (bid < 16) {
        src = W1; sh = W1h; sl = W1l; th = T1h; tl = T1l;
        C = 64; bx = bid & 1; by = bid >> 1;
    } else {
        const int q = bid - 16, j = q >> 6, lo = q & 63;
        bx = lo & 7; by = lo >> 3; C = 256;
        if (j == 0)      { src = W2; sh = W2h; sl = W2l; th = T2h; tl = T2l; }
        else if (j == 1) { src = W3; sh = W3h; sl = W3l; th = T3h; tl = T3l; }
        else             { src = W4; sh = W4h; sl = W4l; th = T4h; tl = T4l; }
    }
    const int R = 256;
    const int tx = threadIdx.x & 31, ty = threadIdx.x >> 5;
    #pragma unroll
    for (int i = 0; i < 32; i += 8) {
        const size_t o = (size_t)(by * 32 + ty + i) * C + bx * 32 + tx;
        const float v = src[o];
        tile[ty + i][tx] = v;
        const half_t h = (half_t)v;
        sh[o] = h; sl[o] = (half_t)(v - (float)h);
    }
    __syncthreads();
    #pragma unroll
    for (int i = 0; i < 32; i += 8) {
        const float v = tile[tx][ty + i];
        const half_t h = (half_t)v;
        const size_t o = (size_t)(bx * 32 + ty + i) * R + by * 32 + tx;
        th[o] = h; tl[o] = (half_t)(v - (float)h);
    }
}

// ---------------- fwd layer: pre = A @ W^T + b; G -> regs; H' = elu -> LDS nxt ----------------
// B-frag global loads double-buffered one k-step ahead.
template<int K, bool WRITE_H>
__device__ __forceinline__
void fwd_layer(const half_t* __restrict__ Ah, const half_t* __restrict__ Al,
               half_t* __restrict__ Nh, half_t* __restrict__ Nl,
               const half_t* __restrict__ Wh, const half_t* __restrict__ Wl,
               const float* __restrict__ bias, float gout[2][4],
               int n0w, int lrow, int kgrp)
{
    const int arow = lrow * LDA;
    const size_t bc0 = (size_t)(n0w + lrow) * K;
    const size_t bc1 = (size_t)(n0w + 16 + lrow) * K;
    const float bb0 = bias[n0w + lrow];
    const float bb1 = bias[n0w + 16 + lrow];

    f32x4 acc[2] = {};
    int ko = kgrp * 8;
    half8 bh0 = *(const half8*)(Wh + bc0 + ko);
    half8 bl0 = *(const half8*)(Wl + bc0 + ko);
    half8 bh1 = *(const half8*)(Wh + bc1 + ko);
    half8 bl1 = *(const half8*)(Wl + bc1 + ko);
    #pragma unroll
    for (int k0 = 0; k0 < K; k0 += 32) {
        half8 nbh0, nbl0, nbh1, nbl1;
        if (k0 + 32 < K) {
            const int ko2 = k0 + 32 + kgrp * 8;
            nbh0 = *(const half8*)(Wh + bc0 + ko2);
            nbl0 = *(const half8*)(Wl + bc0 + ko2);
            nbh1 = *(const half8*)(Wh + bc1 + ko2);
            nbl1 = *(const half8*)(Wl + bc1 + ko2);
        }
        const int koc = k0 + kgrp * 8;
        const half8 ah = *(const half8*)&Ah[arow + koc];
        const half8 al = *(const half8*)&Al[arow + koc];
        acc[0] = MFMA16(ah, bh0, acc[0]);
        acc[1] = MFMA16(ah, bh1, acc[1]);
        acc[0] = MFMA16(ah, bl0, acc[0]);
        acc[1] = MFMA16(ah, bl1, acc[1]);
        acc[0] = MFMA16(al, bh0, acc[0]);
        acc[1] = MFMA16(al, bh1, acc[1]);
        if (k0 + 32 < K) {
            bh0 = nbh0; bl0 = nbl0; bh1 = nbh1; bl1 = nbl1;
        }
    }
    // no barrier here: epilogue writes the OTHER (nxt) buffer
    #pragma unroll
    for (int fn = 0; fn < 2; ++fn) {
        const int col = n0w + fn * 16 + lrow;
        const float bc = fn ? bb1 : bb0;
        #pragma unroll
        for (int r = 0; r < 4; ++r) {
            const int row = kgrp * 4 + r;
            const float pre = acc[fn][r] + bc;
            float g, h;
            if (pre > 0.f) { g = 1.f; h = pre; }
            else           { g = __expf(pre); h = g - 1.f; }
            gout[fn][r] = g;
            if constexpr (WRITE_H) {
                const half_t hh = (half_t)h;
                Nh[row * LDA + col] = hh;
                Nl[row * LDA + col] = (half_t)(h - (float)hh);
            }
        }
    }
    __syncthreads();
}

// ---------------- bwd mid step: C' = (C @ T^T) * G  (G from regs) ----------------
__device__ __forceinline__
void bwd_mid(half_t* __restrict__ Ch, half_t* __restrict__ Cl,
             const half_t* __restrict__ Th, const half_t* __restrict__ Tl,
             const float gpre[2][4], int n0w, int lrow, int kgrp)
{
    const int ar0 = (0 * 16 + lrow) * LDA;
    const int ar1 = (1 * 16 + lrow) * LDA;
    const int ar2 = (2 * 16 + lrow) * LDA;
    const size_t bc0 = (size_t)(n0w + lrow) * 256;
    const size_t bc1 = (size_t)(n0w + 16 + lrow) * 256;

    f32x4 acc[3][2] = {};
    int ko = kgrp * 8;
    half8 bh0 = *(const half8*)(Th + bc0 + ko);
    half8 bl0 = *(const half8*)(Tl + bc0 + ko);
    half8 bh1 = *(const half8*)(Th + bc1 + ko);
    half8 bl1 = *(const half8*)(Tl + bc1 + ko);
    #pragma unroll
    for (int k0 = 0; k0 < 256; k0 += 32) {
        half8 nbh0, nbl0, nbh1, nbl1;
        if (k0 < 224) {
            const int ko2 = k0 + 32 + kgrp * 8;
            nbh0 = *(const half8*)(Th + bc0 + ko2);
            nbl0 = *(const half8*)(Tl + bc0 + ko2);
            nbh1 = *(const half8*)(Th + bc1 + ko2);
            nbl1 = *(const half8*)(Tl + bc1 + ko2);
        }
        const int koc = k0 + kgrp * 8;
        const half8 ah0 = *(const half8*)&Ch[ar0 + koc];
        const half8 al0 = *(const half8*)&Cl[ar0 + koc];
        const half8 ah1 = *(const half8*)&Ch[ar1 + koc];
        const half8 al1 = *(const half8*)&Cl[ar1 + koc];
        const half8 ah2 = *(const half8*)&Ch[ar2 + koc];
        const half8 al2 = *(const half8*)&Cl[ar2 + koc];
        acc[0][0] = MFMA16(ah0, bh0, acc[0][0]);
        acc[1][0] = MFMA16(ah1, bh0, acc[1][0]);
        acc[2][0] = MFMA16(ah2, bh0, acc[2][0]);
        acc[0][1] = MFMA16(ah0, bh1, acc[0][1]);
        acc[1][1] = MFMA16(ah1, bh1, acc[1][1]);
        acc[2][1] = MFMA16(ah2, bh1, acc[2][1]);
        acc[0][0] = MFMA16(ah0, bl0, acc[0][0]);
        acc[1][0] = MFMA16(ah1, bl0, acc[1][0]);
        acc[2][0] = MFMA16(ah2, bl0, acc[2][0]);
        acc[0][1] = MFMA16(ah0, bl1, acc[0][1]);
        acc[1][1] = MFMA16(ah1, bl1, acc[1][1]);
        acc[2][1] = MFMA16(ah2, bl1, acc[2][1]);
        acc[0][0] = MFMA16(al0, bh0, acc[0][0]);
        acc[1][0] = MFMA16(al1, bh0, acc[1][0]);
        acc[2][0] = MFMA16(al2, bh0, acc[2][0]);
        acc[0][1] = MFMA16(al0, bh1, acc[0][1]);
        acc[1][1] = MFMA16(al1, bh1, acc[1][1]);
        acc[2][1] = MFMA16(al2, bh1, acc[2][1]);
        if (k0 < 224) {
            bh0 = nbh0; bl0 = nbl0; bh1 = nbh1; bl1 = nbl1;
        }
    }
    __syncthreads();          // all k-loop reads of C complete
    #pragma unroll
    for (int fn = 0; fn < 2; ++fn) {
        const int col = n0w + fn * 16 + lrow;
        #pragma unroll
        for (int fm = 0; fm < 3; ++fm) {
            #pragma unroll
            for (int r = 0; r < 4; ++r) {
                const int row = fm * 16 + kgrp * 4 + r;
                const float v = acc[fm][fn][r] * gpre[fn][r];
                const half_t h = (half_t)v;
                Ch[row * LDA + col] = h;
                Cl[row * LDA + col] = (half_t)(v - (float)h);
            }
        }
    }
    __syncthreads();
}

// ---------------- fully fused forward+backward ----------------
__global__ __launch_bounds__(512, 4)
void netgrad_fused(const float* __restrict__ x,
                   const half_t* __restrict__ W1h, const half_t* __restrict__ W1l, const float* __restrict__ b1,
                   const half_t* __restrict__ W2h, const half_t* __restrict__ W2l, const float* __restrict__ b2,
                   const half_t* __restrict__ W3h, const half_t* __restrict__ W3l, const float* __restrict__ b3,
                   const half_t* __restrict__ W4h, const half_t* __restrict__ W4l, const float* __restrict__ b4,
                   const float* __restrict__ W5,
                   const half_t* __restrict__ T4h, const half_t* __restrict__ T4l,
                   const half_t* __restrict__ T3h, const half_t* __restrict__ T3l,
                   const half_t* __restrict__ T2h, const half_t* __restrict__ T2l,
                   const half_t* __restrict__ T1h, const half_t* __restrict__ T1l,
                   float* __restrict__ out)
{
    __shared__ half_t Ch[48 * LDA];
    __shared__ half_t Cl[48 * LDA];
    half_t* B0h = Ch;                  // fwd ping buffer: rows 0-15
    half_t* B0l = Cl;
    half_t* B1h = Ch + 16 * LDA;       // fwd pong buffer: rows 16-31
    half_t* B1l = Cl + 16 * LDA;
    const int tid = threadIdx.x;
    const int m0s = blockIdx.x * 16;   // sample base

    // ---- load + split x [16][64] into buf0 ----
    if (tid < 256) {
        const int row = tid >> 4, c4 = (tid & 15) * 4;
        const float4 v = *(const float4*)(x + (size_t)(m0s + row) * 64 + c4);
        const float vv[4] = {v.x, v.y, v.z, v.w};
        #pragma unroll
        for (int j = 0; j < 4; ++j) {
            const half_t h = (half_t)vv[j];
            B0h[row * LDA + c4 + j] = h;
            B0l[row * LDA + c4 + j] = (half_t)(vv[j] - (float)h);
        }
    }
    __syncthreads();

    const int lane = tid & 63, lrow = lane & 15, kgrp = lane >> 4;
    const int wave = tid >> 6;
    const int n0w = wave * 32;

    // ---- forward: G_i stay in registers (lane mapping == bwd consumer) ----
    float G1r[2][4], G2r[2][4], G3r[2][4], G4r[2][4];
    fwd_layer< 64, true >(B0h, B0l, B1h, B1l, W1h, W1l, b1, G1r, n0w, lrow, kgrp);
    fwd_layer<256, true >(B1h, B1l, B0h, B0l, W2h, W2l, b2, G2r, n0w, lrow, kgrp);
    fwd_layer<256, true >(B0h, B0l, B1h, B1l, W3h, W3l, b3, G3r, n0w, lrow, kgrp);
    // prefetch W5 values needed by expand (hide under L4 k-loop)
    float w5v[2][3];
    #pragma unroll
    for (int fn = 0; fn < 2; ++fn) {
        const int k = n0w + fn * 16 + lrow;
        #pragma unroll
        for (int o = 0; o < 3; ++o) w5v[fn][o] = W5[o * 256 + k];
    }
    fwd_layer<256, false>(B1h, B1l, nullptr, nullptr, W4h, W4l, b4, G4r, n0w, lrow, kgrp);
    // barrier inside fwd_layer L4 guarantees all k-loop reads done before expand

    // ---- expand: C0[o*16+s][k] = W5[o][k] * G4[s][k], all from regs ----
    #pragma unroll
    for (int fn = 0; fn < 2; ++fn) {
        const int k = n0w + fn * 16 + lrow;
        #pragma unroll
        for (int o = 0; o < 3; ++o)
            #pragma unroll
            for (int r = 0; r < 4; ++r) {
                const int s = kgrp * 4 + r;
                const float v = w5v[fn][o] * G4r[fn][r];
                const half_t h = (half_t)v;
                Ch[(o * 16 + s) * LDA + k] = h;
                Cl[(o * 16 + s) * LDA + k] = (half_t)(v - (float)h);
            }
    }
    __syncthreads();

    // ---- backward chain ----
    bwd_mid(Ch, Cl, T4h, T4l, G3r, n0w, lrow, kgrp);
    bwd_mid(Ch, Cl, T3h, T3l, G2r, n0w, lrow, kgrp);
    bwd_mid(Ch, Cl, T2h, T2l, G1r, n0w, lrow, kgrp);

    // ---- final: [48][256] @ T1[64][256]^T -> out rows (m0s+s)*3+o ----
    {
        const int fnf  = wave & 3;
        const int colf = fnf * 16 + lrow;
        const size_t bcf = (size_t)colf * 256;
        if (wave < 4) {
            f32x4 acc[2] = {};
            int ko = kgrp * 8;
            half8 bh = *(const half8*)(T1h + bcf + ko);
            half8 bl = *(const half8*)(T1l + bcf + ko);
            #pragma unroll
            for (int k0 = 0; k0 < 256; k0 += 32) {
                half8 nbh, nbl;
                if (k0 < 224) {
                    const int ko2 = k0 + 32 + kgrp * 8;
                    nbh = *(const half8*)(T1h + bcf + ko2);
                    nbl = *(const half8*)(T1l + bcf + ko2);
                }
                const int koc = k0 + kgrp * 8;
                #pragma unroll
                for (int fm = 0; fm < 2; ++fm) {
                    const half8 ah = *(const half8*)&Ch[(fm * 16 + lrow) * LDA + koc];
                    const half8 al = *(const half8*)&Cl[(fm * 16 + lrow) * LDA + koc];
                    acc[fm] = MFMA16(ah, bh, acc[fm]);
                    acc[fm] = MFMA16(ah, bl, acc[fm]);
                    acc[fm] = MFMA16(al, bh, acc[fm]);
                }
                if (k0 < 224) { bh = nbh; bl = nbl; }
            }
            #pragma unroll
            for (int fm = 0; fm < 2; ++fm)
                #pragma unroll
                for (int r = 0; r < 4; ++r) {
                    const int s = kgrp * 4 + r;
                    out[((size_t)(m0s + s) * 3 + fm) * 64 + colf] = acc[fm][r];
                }
        } else {
            f32x4 acc = {};
            int ko = kgrp * 8;
            half8 bh = *(const half8*)(T1h + bcf + ko);
            half8 bl = *(const half8*)(T1l + bcf + ko);
            #pragma unroll
            for (int k0 = 0; k0 < 256; k0 += 32) {
                half8 nbh, nbl;
                if (k0 < 224) {
                    const int ko2 = k0 + 32 + kgrp * 8;
                    nbh = *(const half8*)(T1h + bcf + ko2);
                    nbl = *(const half8*)(T1l + bcf + ko2);
                }
                const int koc = k0 + kgrp * 8;
                const half8 ah = *(const half8*)&Ch[(2 * 16 + lrow) * LDA + koc];
                const half8 al = *(const half8*)&Cl[(2 * 16 + lrow) * LDA + koc];
                acc = MFMA16(ah, bh, acc);
                acc = MFMA16(ah, bl, acc);
                acc = MFMA16(al, bh, acc);
                if (k0 < 224) { bh = nbh; bl = nbl; }
            }
            #pragma unroll
            for (int r = 0; r < 4; ++r) {
                const int s = kgrp * 4 + r;
                out[((size_t)(m0s + s) * 3 + 2) * 64 + colf] = acc[r];
            }
        }
    }
}

extern "C" void kernel_launch(void* const* d_in, const int* in_sizes, int n_in,
                              void* d_out, int out_size, void* d_ws, size_t ws_size,
                              hipStream_t stream)
{
    const float* x  = (const float*)d_in[0];
    const float* W1 = (const float*)d_in[1];
    const float* b1 = (const float*)d_in[2];
    const float* W2 = (const float*)d_in[3];
    const float* b2 = (const float*)d_in[4];
    const float* W3 = (const float*)d_in[5];
    const float* b3 = (const float*)d_in[6];
    const float* W4 = (const float*)d_in[7];
    const float* b4 = (const float*)d_in[8];
    const float* W5 = (const float*)d_in[9];

    // ---- workspace carve (~2.6 MB: weight splits only) ----
    char* p = (char*)d_ws;
    half_t* W1h = (half_t*)p; p += 256 * 64 * 2;
    half_t* W1l = (half_t*)p; p += 256 * 64 * 2;
    half_t* T1h = (half_t*)p; p += 64 * 256 * 2;
    half_t* T1l = (half_t*)p; p += 64 * 256 * 2;
    half_t* W2h = (half_t*)p; p += 256 * 256 * 2;
    half_t* W2l = (half_t*)p; p += 256 * 256 * 2;
    half_t* T2h = (half_t*)p; p += 256 * 256 * 2;
    half_t* T2l = (half_t*)p; p += 256 * 256 * 2;
    half_t* W3h = (half_t*)p; p += 256 * 256 * 2;
    half_t* W3l = (half_t*)p; p += 256 * 256 * 2;
    half_t* T3h = (half_t*)p; p += 256 * 256 * 2;
    half_t* T3l = (half_t*)p; p += 256 * 256 * 2;
    half_t* W4h = (half_t*)p; p += 256 * 256 * 2;
    half_t* W4l = (half_t*)p; p += 256 * 256 * 2;
    half_t* T4h = (half_t*)p; p += 256 * 256 * 2;
    half_t* T4l = (half_t*)p; p += 256 * 256 * 2;

    prep_split<<<208, 256, 0, stream>>>(W1, W2, W3, W4,
        W1h, W1l, T1h, T1l, W2h, W2l, T2h, T2l,
        W3h, W3l, T3h, T3l, W4h, W4l, T4h, T4l);

    netgrad_fused<<<Bsz / 16, 512, 0, stream>>>(x,
        W1h, W1l, b1,  W2h, W2l, b2,  W3h, W3l, b3,  W4h, W4l, b4,
        W5,  T4h, T4l, T3h, T3l, T2h, T2l, T1h, T1l,
        (float*)d_out);
}